// Round 1
// baseline (40186.465 us; speedup 1.0000x reference)
//
#include <hip/hip_runtime.h>
#include <hip/hip_fp16.h>

#define NEG_INF_F (-1e30f)
#define MAX_S 2048
#define MAX_C 3008

// Order-preserving encode of float into unsigned for atomicMax.
__device__ __forceinline__ unsigned enc_f(float x) {
  unsigned u = __float_as_uint(x);
  return u ^ (unsigned)(((int)u >> 31) | 0x80000000);
}
__device__ __forceinline__ float dec_f(unsigned e) {
  unsigned mask = ((int)e >= 0) ? 0xFFFFFFFFu : 0x80000000u;
  return __uint_as_float(e ^ mask);
}

__global__ void pack_arcs_kernel(const int* __restrict__ src, const int* __restrict__ dst,
                                 const int* __restrict__ pdf, const float* __restrict__ w,
                                 uint2* __restrict__ out, int n) {
  int i = blockIdx.x * blockDim.x + threadIdx.x;
  if (i < n) {
    unsigned short wh = __half_as_ushort(__float2half_rn(w[i]));
    out[i] = make_uint2((unsigned)src[i] | ((unsigned)dst[i] << 16),
                        (unsigned)pdf[i] | ((unsigned)wh << 16));
  }
}

// One block per FSA chain. Blocks [0,B) = denominator chains, [B,2B) = numerator chains.
template<bool PACKED>
__global__ __launch_bounds__(1024)
void fsa_forward_kernel(
    const float* __restrict__ ll, const int* __restrict__ seqlen,
    const uint2* __restrict__ den_arcs,
    const int* __restrict__ den_src, const int* __restrict__ den_dst,
    const int* __restrict__ den_pdf, const float* __restrict__ den_w,
    int A_den, const float* __restrict__ den_init, const float* __restrict__ den_final, int S_den,
    const uint2* __restrict__ num_arcs,
    const int* __restrict__ num_src, const int* __restrict__ num_dst,
    const int* __restrict__ num_pdf, const float* __restrict__ num_w,
    int A_num, const float* __restrict__ num_init, const float* __restrict__ num_final, int S_num,
    int T, int C, int B, float* __restrict__ out_llh)
{
  __shared__ float    alpha[MAX_S];
  __shared__ unsigned menc[MAX_S];
  __shared__ float    msafe[MAX_S];
  __shared__ float    ssum[MAX_S];
  __shared__ float    llrow[MAX_C];

  const int tid = threadIdx.x;
  const int nt  = blockDim.x;
  const bool is_den = ((int)blockIdx.x) < B;
  const int b = is_den ? (int)blockIdx.x : ((int)blockIdx.x - B);
  const int S = is_den ? S_den : S_num;
  const int A = is_den ? A_den : A_num;
  const float* init = is_den ? den_init  : num_init;
  const float* fin  = is_den ? den_final : num_final;
  const uint2* arcs = is_den ? den_arcs : (num_arcs + (size_t)b * A_num);
  const int*   asrc = is_den ? den_src  : (num_src + (size_t)b * A_num);
  const int*   adst = is_den ? den_dst  : (num_dst + (size_t)b * A_num);
  const int*   apdf = is_den ? den_pdf  : (num_pdf + (size_t)b * A_num);
  const float* aw   = is_den ? den_w    : (num_w   + (size_t)b * A_num);

  for (int s = tid; s < S; s += nt) {
    alpha[s] = init[s];
    menc[s]  = 0u;
    ssum[s]  = 0.0f;
  }
  __syncthreads();

  const int L = seqlen[b];               // alpha frozen for t >= L -> just stop there
  const float* llb = ll + ((size_t)b * T) * C;

  for (int t = 0; t < L; ++t) {
    const float* row = llb + (size_t)t * C;
    for (int i = tid; i < C; i += nt) llrow[i] = row[i];
    __syncthreads();

    // pass 1: per-dst max of scores (int-encoded atomicMax)
    for (int i = tid; i < A; i += nt) {
      int src, dst, pdf; float w;
      if (PACKED) {
        uint2 a2 = arcs[i];
        src = (int)(a2.x & 0xFFFFu); dst = (int)(a2.x >> 16);
        pdf = (int)(a2.y & 0xFFFFu);
        w = __half2float(__ushort_as_half((unsigned short)(a2.y >> 16)));
      } else {
        src = asrc[i]; dst = adst[i]; pdf = apdf[i]; w = aw[i];
      }
      float score = alpha[src] + w + llrow[pdf];
      atomicMax(&menc[dst], enc_f(score));
    }
    __syncthreads();

    // pass 1.5: decode m_safe (reference: where(m > NEG_INF/2, m, 0))
    for (int s = tid; s < S; s += nt) {
      float m = dec_f(menc[s]);
      msafe[s] = (m > -5e29f) ? m : 0.0f;
    }
    __syncthreads();

    // pass 2: per-dst sum of exp(score - m_safe)
    for (int i = tid; i < A; i += nt) {
      int src, dst, pdf; float w;
      if (PACKED) {
        uint2 a2 = arcs[i];
        src = (int)(a2.x & 0xFFFFu); dst = (int)(a2.x >> 16);
        pdf = (int)(a2.y & 0xFFFFu);
        w = __half2float(__ushort_as_half((unsigned short)(a2.y >> 16)));
      } else {
        src = asrc[i]; dst = adst[i]; pdf = apdf[i]; w = aw[i];
      }
      float score = alpha[src] + w + llrow[pdf];
      atomicAdd(&ssum[dst], __expf(score - msafe[dst]));
    }
    __syncthreads();

    // pass 3: alpha update + reset accumulators
    for (int s = tid; s < S; s += nt) {
      float sum = ssum[s];
      alpha[s] = (sum > 0.0f) ? (__logf(sum) + msafe[s]) : NEG_INF_F;
      menc[s] = 0u;
      ssum[s] = 0.0f;
    }
    __syncthreads();
  }

  // final logsumexp(alpha + final_logp)
  float lm = -3.0e38f;
  for (int s = tid; s < S; s += nt) lm = fmaxf(lm, alpha[s] + fin[s]);
  for (int off = 32; off; off >>= 1) lm = fmaxf(lm, __shfl_down(lm, off));
  const int nwaves = nt >> 6;
  if ((tid & 63) == 0) msafe[tid >> 6] = lm;
  __syncthreads();
  if (tid < 64) {
    float v = (tid < nwaves) ? msafe[tid] : -3.0e38f;
    for (int off = 32; off; off >>= 1) v = fmaxf(v, __shfl_down(v, off));
    if (tid == 0) msafe[MAX_S - 1] = v;
  }
  __syncthreads();
  const float M = msafe[MAX_S - 1];

  float ls = 0.0f;
  for (int s = tid; s < S; s += nt) ls += __expf(alpha[s] + fin[s] - M);
  for (int off = 32; off; off >>= 1) ls += __shfl_down(ls, off);
  if ((tid & 63) == 0) ssum[tid >> 6] = ls;
  __syncthreads();
  if (tid < 64) {
    float v = (tid < nwaves) ? ssum[tid] : 0.0f;
    for (int off = 32; off; off >>= 1) v += __shfl_down(v, off);
    if (tid == 0) out_llh[(is_den ? 0 : B) + b] = __logf(v) + M;
  }
}

// loss = sum_b (den_llh[b] - num_llh[b])
__global__ void final_loss_kernel(const float* __restrict__ llh, int B, float* __restrict__ out) {
  int lane = threadIdx.x;
  float v = (lane < B) ? (llh[lane] - llh[B + lane]) : 0.0f;
  for (int off = 32; off; off >>= 1) v += __shfl_down(v, off);
  if (lane == 0) out[0] = v;
}

extern "C" void kernel_launch(void* const* d_in, const int* in_sizes, int n_in,
                              void* d_out, int out_size, void* d_ws, size_t ws_size,
                              hipStream_t stream) {
  const float* ll        = (const float*)d_in[0];
  const int*   seqlen    = (const int*)  d_in[1];
  const int*   num_src   = (const int*)  d_in[2];
  const int*   num_dst   = (const int*)  d_in[3];
  const int*   num_pdf   = (const int*)  d_in[4];
  const float* num_w     = (const float*)d_in[5];
  const float* num_init  = (const float*)d_in[6];
  const float* num_final = (const float*)d_in[7];
  const int*   den_src   = (const int*)  d_in[8];
  const int*   den_dst   = (const int*)  d_in[9];
  const int*   den_pdf   = (const int*)  d_in[10];
  const float* den_w     = (const float*)d_in[11];
  const float* den_init  = (const float*)d_in[12];
  const float* den_final = (const float*)d_in[13];

  const int B     = in_sizes[1];
  const int A_num = in_sizes[2] / B;
  const int S_num = in_sizes[6];
  const int A_den = in_sizes[8];
  const int S_den = in_sizes[12];
  const int T     = 500;                       // problem spec
  const int C     = in_sizes[0] / (B * T);

  const size_t den_bytes = (size_t)A_den * 8;
  const size_t num_bytes = (size_t)B * A_num * 8;
  const size_t need = den_bytes + num_bytes + (size_t)2 * B * 4;
  const bool packed = ws_size >= need;

  uint2* den_packed = nullptr;
  uint2* num_packed = nullptr;
  float* llh        = nullptr;

  if (packed) {
    den_packed = (uint2*)d_ws;
    num_packed = (uint2*)((char*)d_ws + den_bytes);
    llh        = (float*)((char*)d_ws + den_bytes + num_bytes);
    pack_arcs_kernel<<<(A_den + 255) / 256, 256, 0, stream>>>(
        den_src, den_dst, den_pdf, den_w, den_packed, A_den);
    pack_arcs_kernel<<<(B * A_num + 255) / 256, 256, 0, stream>>>(
        num_src, num_dst, num_pdf, num_w, num_packed, B * A_num);
  } else {
    llh = (float*)d_ws;  // only needs 2*B floats
  }

  dim3 grid(2 * B), block(1024);
  if (packed) {
    fsa_forward_kernel<true><<<grid, block, 0, stream>>>(
        ll, seqlen,
        den_packed, den_src, den_dst, den_pdf, den_w, A_den, den_init, den_final, S_den,
        num_packed, num_src, num_dst, num_pdf, num_w, A_num, num_init, num_final, S_num,
        T, C, B, llh);
  } else {
    fsa_forward_kernel<false><<<grid, block, 0, stream>>>(
        ll, seqlen,
        nullptr, den_src, den_dst, den_pdf, den_w, A_den, den_init, den_final, S_den,
        nullptr, num_src, num_dst, num_pdf, num_w, A_num, num_init, num_final, S_num,
        T, C, B, llh);
  }

  final_loss_kernel<<<1, 64, 0, stream>>>(llh, B, (float*)d_out);
}

// Round 2
// 20995.082 us; speedup vs baseline: 1.9141x; 1.9141x over previous
//
#include <hip/hip_runtime.h>

#define NEG_INF_F (-1e30f)
#define MAX_S 2048
#define MAX_C 3008

// ============================ CSR build (deterministic) ============================

__global__ void zero_kernel(int* __restrict__ p, int n) {
  int i = blockIdx.x * blockDim.x + threadIdx.x;
  if (i < n) p[i] = 0;
}

// grid (ceil(A/256), nfsa)
__global__ void hist_kernel(const int* __restrict__ dst, int A, int A_stride,
                            int* __restrict__ cnt, int S) {
  int b = blockIdx.y;
  int i = blockIdx.x * blockDim.x + threadIdx.x;
  if (i < A) atomicAdd(&cnt[b * S + dst[(size_t)b * A_stride + i]], 1);
}

// grid = nfsa blocks of 1024; S <= 2047. Exclusive scan -> row_ptr[S+1].
__global__ __launch_bounds__(1024) void scan_kernel(const int* __restrict__ cnt,
                                                    int* __restrict__ rp, int S) {
  __shared__ int buf[2][2048];
  const int tid = threadIdx.x;
  const int b = blockIdx.x;
  const int* c = cnt + (size_t)b * S;
  int* r = rp + (size_t)b * (S + 1);
  for (int u = 0; u < 2; ++u) {
    int i = tid + u * 1024;
    buf[0][i] = (i < S) ? c[i] : 0;
  }
  __syncthreads();
  int cur = 0;
  for (int off = 1; off < 2048; off <<= 1) {
    for (int u = 0; u < 2; ++u) {
      int i = tid + u * 1024;
      buf[cur ^ 1][i] = buf[cur][i] + ((i >= off) ? buf[cur][i - off] : 0);
    }
    __syncthreads();
    cur ^= 1;
  }
  for (int u = 0; u < 2; ++u) {
    int i = tid + u * 1024;
    if (i <= S) r[i] = (i == 0) ? 0 : buf[cur][i - 1];
  }
}

// grid (ceil(S/256), nfsa). Thread s scans all arcs in index order -> stable CSR.
__global__ void fill_kernel(const int* __restrict__ src, const int* __restrict__ dst,
                            const int* __restrict__ pdf, const float* __restrict__ w,
                            int A, int A_stride, const int* __restrict__ rp, int S,
                            uint2* __restrict__ meta, int meta_stride) {
  int b = blockIdx.y;
  int s = blockIdx.x * blockDim.x + threadIdx.x;
  if (s >= S) return;
  const int*   sb = src + (size_t)b * A_stride;
  const int*   db = dst + (size_t)b * A_stride;
  const int*   pb = pdf + (size_t)b * A_stride;
  const float* wb = w   + (size_t)b * A_stride;
  uint2* mb = meta + (size_t)b * meta_stride;
  int p = rp[(size_t)b * (S + 1) + s];
  for (int i = 0; i < A; ++i) {
    if (db[i] == s) {
      mb[p] = make_uint2((unsigned)sb[i] | ((unsigned)pb[i] << 16), __float_as_uint(wb[i]));
      ++p;
    }
  }
}

// ============================ CSR forward ============================
// Blocks [0,B) = denominator chains, [B,2B) = numerator chains.
// Per thread: <=2 dst states, online logsumexp in registers. No atomics.
__global__ __launch_bounds__(1024)
void fsa_forward_csr(const float* __restrict__ ll, const int* __restrict__ seqlen,
                     const uint2* __restrict__ den_meta, const int* __restrict__ den_rp, int S_den,
                     const uint2* __restrict__ num_meta, const int* __restrict__ num_rp,
                     int A_num, int S_num,
                     const float* __restrict__ den_init, const float* __restrict__ den_final,
                     const float* __restrict__ num_init, const float* __restrict__ num_final,
                     int T, int C, int B, float* __restrict__ out_llh)
{
  __shared__ float alpha[MAX_S];
  __shared__ float redbuf[16];

  const int tid = threadIdx.x;
  const int nt  = blockDim.x;     // 1024
  const bool is_den = ((int)blockIdx.x) < B;
  const int b = is_den ? (int)blockIdx.x : ((int)blockIdx.x - B);
  const int S = is_den ? S_den : S_num;
  const float* init = is_den ? den_init  : num_init;
  const float* fin  = is_den ? den_final : num_final;
  const uint2* meta = is_den ? den_meta : (num_meta + (size_t)b * A_num);
  const int*   rp   = is_den ? den_rp   : (num_rp   + (size_t)b * (S_num + 1));

  for (int s = tid; s < S; s += nt) alpha[s] = init[s];

  // Row bounds are loop-invariant: preload into registers.
  int rs[2] = {0, 0}, re[2] = {0, 0};
  for (int u = 0; u < 2; ++u) {
    int s = tid + u * nt;
    if (s < S) { rs[u] = rp[s]; re[u] = rp[s + 1]; }
  }

  const int L = seqlen[b];        // alpha frozen for t >= L -> stop there
  const float* llb = ll + ((size_t)b * T) * C;
  __syncthreads();

  for (int t = 0; t < L; ++t) {
    const float* lt = llb + (size_t)t * C;   // 12KB row, L1-resident gathers
    float nv[2];
    for (int u = 0; u < 2; ++u) {
      nv[u] = NEG_INF_F;
      int s = tid + u * nt;
      if (s < S) {
        float mm = NEG_INF_F, ss = 0.0f;
        for (int k = rs[u]; k < re[u]; ++k) {
          uint2 a = meta[k];
          float sc = alpha[a.x & 0xFFFFu] + __uint_as_float(a.y) + lt[a.x >> 16];
          // branchless online logsumexp step (2 exps, no divergence)
          float nm = fmaxf(mm, sc);
          ss = ss * __expf(mm - nm) + __expf(sc - nm);
          mm = nm;
        }
        nv[u] = (ss > 0.0f) ? (__logf(ss) + mm) : NEG_INF_F;
      }
    }
    __syncthreads();               // all reads of old alpha done
    for (int u = 0; u < 2; ++u) {
      int s = tid + u * nt;
      if (s < S) alpha[s] = nv[u];
    }
    __syncthreads();               // new alpha visible
  }

  // final logsumexp(alpha + final_logp)
  const int nwaves = nt >> 6;
  float lm = -3.0e38f;
  for (int s = tid; s < S; s += nt) lm = fmaxf(lm, alpha[s] + fin[s]);
  for (int off = 32; off; off >>= 1) lm = fmaxf(lm, __shfl_down(lm, off));
  if ((tid & 63) == 0) redbuf[tid >> 6] = lm;
  __syncthreads();
  if (tid < 64) {
    float v = (tid < nwaves) ? redbuf[tid] : -3.0e38f;
    for (int off = 32; off; off >>= 1) v = fmaxf(v, __shfl_down(v, off));
    if (tid == 0) redbuf[0] = v;
  }
  __syncthreads();
  const float M = redbuf[0];

  float ls = 0.0f;
  for (int s = tid; s < S; s += nt) ls += __expf(alpha[s] + fin[s] - M);
  for (int off = 32; off; off >>= 1) ls += __shfl_down(ls, off);
  __syncthreads();                 // before redbuf reuse
  if ((tid & 63) == 0) redbuf[tid >> 6] = ls;
  __syncthreads();
  if (tid < 64) {
    float v = (tid < nwaves) ? redbuf[tid] : 0.0f;
    for (int off = 32; off; off >>= 1) v += __shfl_down(v, off);
    if (tid == 0) out_llh[(is_den ? 0 : B) + b] = __logf(v) + M;
  }
}

// ============================ fallback (round-1 proven path, tiny ws) ============================

__device__ __forceinline__ unsigned enc_f(float x) {
  unsigned u = __float_as_uint(x);
  return u ^ (unsigned)(((int)u >> 31) | 0x80000000);
}
__device__ __forceinline__ float dec_f(unsigned e) {
  unsigned mask = ((int)e >= 0) ? 0xFFFFFFFFu : 0x80000000u;
  return __uint_as_float(e ^ mask);
}

__global__ __launch_bounds__(1024)
void fsa_forward_fallback(
    const float* __restrict__ ll, const int* __restrict__ seqlen,
    const int* __restrict__ den_src, const int* __restrict__ den_dst,
    const int* __restrict__ den_pdf, const float* __restrict__ den_w,
    int A_den, const float* __restrict__ den_init, const float* __restrict__ den_final, int S_den,
    const int* __restrict__ num_src, const int* __restrict__ num_dst,
    const int* __restrict__ num_pdf, const float* __restrict__ num_w,
    int A_num, const float* __restrict__ num_init, const float* __restrict__ num_final, int S_num,
    int T, int C, int B, float* __restrict__ out_llh)
{
  __shared__ float    alpha[MAX_S];
  __shared__ unsigned menc[MAX_S];
  __shared__ float    msafe[MAX_S];
  __shared__ float    ssum[MAX_S];
  __shared__ float    llrow[MAX_C];

  const int tid = threadIdx.x;
  const int nt  = blockDim.x;
  const bool is_den = ((int)blockIdx.x) < B;
  const int b = is_den ? (int)blockIdx.x : ((int)blockIdx.x - B);
  const int S = is_den ? S_den : S_num;
  const int A = is_den ? A_den : A_num;
  const float* init = is_den ? den_init  : num_init;
  const float* fin  = is_den ? den_final : num_final;
  const int*   asrc = is_den ? den_src  : (num_src + (size_t)b * A_num);
  const int*   adst = is_den ? den_dst  : (num_dst + (size_t)b * A_num);
  const int*   apdf = is_den ? den_pdf  : (num_pdf + (size_t)b * A_num);
  const float* aw   = is_den ? den_w    : (num_w   + (size_t)b * A_num);

  for (int s = tid; s < S; s += nt) { alpha[s] = init[s]; menc[s] = 0u; ssum[s] = 0.0f; }
  __syncthreads();

  const int L = seqlen[b];
  const float* llb = ll + ((size_t)b * T) * C;

  for (int t = 0; t < L; ++t) {
    const float* row = llb + (size_t)t * C;
    for (int i = tid; i < C; i += nt) llrow[i] = row[i];
    __syncthreads();
    for (int i = tid; i < A; i += nt) {
      float score = alpha[asrc[i]] + aw[i] + llrow[apdf[i]];
      atomicMax(&menc[adst[i]], enc_f(score));
    }
    __syncthreads();
    for (int s = tid; s < S; s += nt) {
      float m = dec_f(menc[s]);
      msafe[s] = (m > -5e29f) ? m : 0.0f;
    }
    __syncthreads();
    for (int i = tid; i < A; i += nt) {
      int d = adst[i];
      float score = alpha[asrc[i]] + aw[i] + llrow[apdf[i]];
      atomicAdd(&ssum[d], __expf(score - msafe[d]));
    }
    __syncthreads();
    for (int s = tid; s < S; s += nt) {
      float sum = ssum[s];
      alpha[s] = (sum > 0.0f) ? (__logf(sum) + msafe[s]) : NEG_INF_F;
      menc[s] = 0u; ssum[s] = 0.0f;
    }
    __syncthreads();
  }

  float lm = -3.0e38f;
  for (int s = tid; s < S; s += nt) lm = fmaxf(lm, alpha[s] + fin[s]);
  for (int off = 32; off; off >>= 1) lm = fmaxf(lm, __shfl_down(lm, off));
  const int nwaves = nt >> 6;
  if ((tid & 63) == 0) msafe[tid >> 6] = lm;
  __syncthreads();
  if (tid < 64) {
    float v = (tid < nwaves) ? msafe[tid] : -3.0e38f;
    for (int off = 32; off; off >>= 1) v = fmaxf(v, __shfl_down(v, off));
    if (tid == 0) msafe[MAX_S - 1] = v;
  }
  __syncthreads();
  const float M = msafe[MAX_S - 1];
  float ls = 0.0f;
  for (int s = tid; s < S; s += nt) ls += __expf(alpha[s] + fin[s] - M);
  for (int off = 32; off; off >>= 1) ls += __shfl_down(ls, off);
  if ((tid & 63) == 0) ssum[tid >> 6] = ls;
  __syncthreads();
  if (tid < 64) {
    float v = (tid < nwaves) ? ssum[tid] : 0.0f;
    for (int off = 32; off; off >>= 1) v += __shfl_down(v, off);
    if (tid == 0) out_llh[(is_den ? 0 : B) + b] = __logf(v) + M;
  }
}

// loss = sum_b (den_llh[b] - num_llh[b])
__global__ void final_loss_kernel(const float* __restrict__ llh, int B, float* __restrict__ out) {
  int lane = threadIdx.x;
  float v = (lane < B) ? (llh[lane] - llh[B + lane]) : 0.0f;
  for (int off = 32; off; off >>= 1) v += __shfl_down(v, off);
  if (lane == 0) out[0] = v;
}

extern "C" void kernel_launch(void* const* d_in, const int* in_sizes, int n_in,
                              void* d_out, int out_size, void* d_ws, size_t ws_size,
                              hipStream_t stream) {
  const float* ll        = (const float*)d_in[0];
  const int*   seqlen    = (const int*)  d_in[1];
  const int*   num_src   = (const int*)  d_in[2];
  const int*   num_dst   = (const int*)  d_in[3];
  const int*   num_pdf   = (const int*)  d_in[4];
  const float* num_w     = (const float*)d_in[5];
  const float* num_init  = (const float*)d_in[6];
  const float* num_final = (const float*)d_in[7];
  const int*   den_src   = (const int*)  d_in[8];
  const int*   den_dst   = (const int*)  d_in[9];
  const int*   den_pdf   = (const int*)  d_in[10];
  const float* den_w     = (const float*)d_in[11];
  const float* den_init  = (const float*)d_in[12];
  const float* den_final = (const float*)d_in[13];

  const int B     = in_sizes[1];
  const int A_num = in_sizes[2] / B;
  const int S_num = in_sizes[6];
  const int A_den = in_sizes[8];
  const int S_den = in_sizes[12];
  const int T     = 500;                       // problem spec
  const int C     = in_sizes[0] / (B * T);

  // workspace layout
  size_t off = 0;
  auto alloc = [&](size_t bytes, size_t align) -> size_t {
    off = (off + align - 1) / align * align;
    size_t r = off; off += bytes; return r;
  };
  size_t o_den_meta = alloc((size_t)A_den * 8, 8);
  size_t o_num_meta = alloc((size_t)B * A_num * 8, 8);
  size_t o_den_rp   = alloc((size_t)(S_den + 1) * 4, 4);
  size_t o_num_rp   = alloc((size_t)B * (S_num + 1) * 4, 4);
  size_t o_den_cnt  = alloc((size_t)S_den * 4, 4);
  size_t o_num_cnt  = alloc((size_t)B * S_num * 4, 4);   // contiguous with den_cnt
  size_t o_llh      = alloc((size_t)2 * B * 4, 4);
  const bool use_csr = (off <= ws_size) && (S_den <= 2047) && (S_num <= 2047) && (C <= 65536);

  char* wsb = (char*)d_ws;
  float* llh = (float*)(wsb + (use_csr ? o_llh : 0));

  if (use_csr) {
    uint2* den_meta = (uint2*)(wsb + o_den_meta);
    uint2* num_meta = (uint2*)(wsb + o_num_meta);
    int*   den_rp   = (int*)(wsb + o_den_rp);
    int*   num_rp   = (int*)(wsb + o_num_rp);
    int*   den_cnt  = (int*)(wsb + o_den_cnt);
    int*   num_cnt  = (int*)(wsb + o_num_cnt);

    int ztot = S_den + B * S_num;
    zero_kernel<<<(ztot + 255) / 256, 256, 0, stream>>>(den_cnt, ztot);

    hist_kernel<<<dim3((A_den + 255) / 256, 1), 256, 0, stream>>>(den_dst, A_den, A_den, den_cnt, S_den);
    hist_kernel<<<dim3((A_num + 255) / 256, B), 256, 0, stream>>>(num_dst, A_num, A_num, num_cnt, S_num);

    scan_kernel<<<1, 1024, 0, stream>>>(den_cnt, den_rp, S_den);
    scan_kernel<<<B, 1024, 0, stream>>>(num_cnt, num_rp, S_num);

    fill_kernel<<<dim3((S_den + 255) / 256, 1), 256, 0, stream>>>(
        den_src, den_dst, den_pdf, den_w, A_den, A_den, den_rp, S_den, den_meta, A_den);
    fill_kernel<<<dim3((S_num + 255) / 256, B), 256, 0, stream>>>(
        num_src, num_dst, num_pdf, num_w, A_num, A_num, num_rp, S_num, num_meta, A_num);

    fsa_forward_csr<<<2 * B, 1024, 0, stream>>>(
        ll, seqlen, den_meta, den_rp, S_den, num_meta, num_rp, A_num, S_num,
        den_init, den_final, num_init, num_final, T, C, B, llh);
  } else {
    fsa_forward_fallback<<<2 * B, 1024, 0, stream>>>(
        ll, seqlen,
        den_src, den_dst, den_pdf, den_w, A_den, den_init, den_final, S_den,
        num_src, num_dst, num_pdf, num_w, A_num, num_init, num_final, S_num,
        T, C, B, llh);
  }

  final_loss_kernel<<<1, 64, 0, stream>>>(llh, B, (float*)d_out);
}

// Round 3
// 6312.289 us; speedup vs baseline: 6.3664x; 3.3261x over previous
//
#include <hip/hip_runtime.h>

#define NEG_INF_F (-1e30f)
#define MAX_S 2048
#define MAX_C 3008
#define NCH   128

// ============================ build helpers (deterministic) ============================

__global__ void zero_kernel(int* __restrict__ p, int n) {
  int i = blockIdx.x * blockDim.x + threadIdx.x;
  if (i < n) p[i] = 0;
}

// per-b histogram (numerator): grid (ceil(A/256), B)
__global__ void hist_kernel(const int* __restrict__ dst, int A, int A_stride,
                            int* __restrict__ cnt, int S) {
  int b = blockIdx.y;
  int i = blockIdx.x * blockDim.x + threadIdx.x;
  if (i < A) atomicAdd(&cnt[b * S + dst[(size_t)b * A_stride + i]], 1);
}

// chunked histogram (denominator): grid NCH blocks
__global__ void hist_chunk_kernel(const int* __restrict__ dst, int A, int chunk, int S,
                                  int* __restrict__ hist) {
  int c = blockIdx.x;
  int i1 = min(A, (c + 1) * chunk);
  for (int i = c * chunk + threadIdx.x; i < i1; i += blockDim.x)
    atomicAdd(&hist[c * S + dst[i]], 1);
}

__global__ void colsum_kernel(const int* __restrict__ hist, int nch, int S,
                              int* __restrict__ cnt) {
  int s = blockIdx.x * blockDim.x + threadIdx.x;
  if (s < S) {
    int t = 0;
    for (int c = 0; c < nch; ++c) t += hist[c * S + s];
    cnt[s] = t;
  }
}

// grid = nfsa blocks of 1024; S <= 2047. Exclusive scan -> row_ptr[S+1].
__global__ __launch_bounds__(1024) void scan_kernel(const int* __restrict__ cnt,
                                                    int* __restrict__ rp, int S) {
  __shared__ int buf[2][2048];
  const int tid = threadIdx.x;
  const int b = blockIdx.x;
  const int* c = cnt + (size_t)b * S;
  int* r = rp + (size_t)b * (S + 1);
  for (int u = 0; u < 2; ++u) {
    int i = tid + u * 1024;
    buf[0][i] = (i < S) ? c[i] : 0;
  }
  __syncthreads();
  int cur = 0;
  for (int off = 1; off < 2048; off <<= 1) {
    for (int u = 0; u < 2; ++u) {
      int i = tid + u * 1024;
      buf[cur ^ 1][i] = buf[cur][i] + ((i >= off) ? buf[cur][i - off] : 0);
    }
    __syncthreads();
    cur ^= 1;
  }
  for (int u = 0; u < 2; ++u) {
    int i = tid + u * 1024;
    if (i <= S) r[i] = (i == 0) ? 0 : buf[cur][i - 1];
  }
}

// in-place: hist[c][s] -> starting offset for (chunk c, state s)
__global__ void off_kernel(int* __restrict__ hist, int nch, int S, const int* __restrict__ rp) {
  int s = blockIdx.x * blockDim.x + threadIdx.x;
  if (s < S) {
    int run = rp[s];
    for (int c = 0; c < nch; ++c) {
      int h = hist[c * S + s];
      hist[c * S + s] = run;
      run += h;
    }
  }
}

// grid (ceil(S/256), NCH): thread (s,c) scans chunk c in original order -> stable CSR
__global__ void fill_chunk_kernel(const int* __restrict__ src, const int* __restrict__ dst,
                                  const int* __restrict__ pdf, const float* __restrict__ w,
                                  int A, int chunk, int S, const int* __restrict__ hoff,
                                  uint2* __restrict__ meta) {
  int c = blockIdx.y;
  int s = blockIdx.x * blockDim.x + threadIdx.x;
  if (s >= S) return;
  int i1 = min(A, (c + 1) * chunk);
  int p = hoff[c * S + s];
  for (int i = c * chunk; i < i1; ++i) {
    if (dst[i] == s) {
      meta[p++] = make_uint2((unsigned)src[i] | ((unsigned)pdf[i] << 16), __float_as_uint(w[i]));
    }
  }
}

// serial per-state fill (numerator, tiny): grid (ceil(S/256), B)
__global__ void fill_kernel(const int* __restrict__ src, const int* __restrict__ dst,
                            const int* __restrict__ pdf, const float* __restrict__ w,
                            int A, int A_stride, const int* __restrict__ rp, int S,
                            uint2* __restrict__ meta, int meta_stride) {
  int b = blockIdx.y;
  int s = blockIdx.x * blockDim.x + threadIdx.x;
  if (s >= S) return;
  const int*   sb = src + (size_t)b * A_stride;
  const int*   db = dst + (size_t)b * A_stride;
  const int*   pb = pdf + (size_t)b * A_stride;
  const float* wb = w   + (size_t)b * A_stride;
  uint2* mb = meta + (size_t)b * meta_stride;
  int p = rp[(size_t)b * (S + 1) + s];
  for (int i = 0; i < A; ++i) {
    if (db[i] == s) {
      mb[p] = make_uint2((unsigned)sb[i] | ((unsigned)pb[i] << 16), __float_as_uint(wb[i]));
      ++p;
    }
  }
}

// ============================ CSR forward v2: LDS ll-row + chunk-4 LSE ============================
// Blocks [0,B) = denominator chains, [B,2B) = numerator chains.
__global__ __launch_bounds__(1024)
void fsa_forward_csr2(const float* __restrict__ ll, const int* __restrict__ seqlen,
                      const uint2* __restrict__ den_meta, const int* __restrict__ den_rp, int S_den,
                      const uint2* __restrict__ num_meta, const int* __restrict__ num_rp,
                      int A_num, int S_num,
                      const float* __restrict__ den_init, const float* __restrict__ den_final,
                      const float* __restrict__ num_init, const float* __restrict__ num_final,
                      int T, int C, int B, float* __restrict__ out_llh)
{
  __shared__ float alpha[MAX_S];
  __shared__ float llrow[MAX_C];
  __shared__ float redbuf[16];

  const int tid = threadIdx.x;
  const int nt  = blockDim.x;     // 1024
  const bool is_den = ((int)blockIdx.x) < B;
  const int b = is_den ? (int)blockIdx.x : ((int)blockIdx.x - B);
  const int S = is_den ? S_den : S_num;
  const float* init = is_den ? den_init  : num_init;
  const float* fin  = is_den ? den_final : num_final;
  const uint2* meta = is_den ? den_meta : (num_meta + (size_t)b * A_num);
  const int*   rp   = is_den ? den_rp   : (num_rp   + (size_t)b * (S_num + 1));

  for (int s = tid; s < S; s += nt) alpha[s] = init[s];

  int rs[2] = {0, 0}, re[2] = {0, 0};
  for (int u = 0; u < 2; ++u) {
    int s = tid + u * nt;
    if (s < S) { rs[u] = rp[s]; re[u] = rp[s + 1]; }
  }

  const int L = seqlen[b];        // alpha frozen for t >= L -> stop there
  const float* llb = ll + ((size_t)b * T) * C;
  const int nvec = C >> 2;
  const bool v4 = ((C & 3) == 0) && ((((uintptr_t)llb) & 15) == 0);
  __syncthreads();

  for (int t = 0; t < L; ++t) {
    // stage ll_t row into LDS (float4 coalesced)
    const float* row = llb + (size_t)t * C;
    if (v4) {
      const float4* row4 = (const float4*)row;
      for (int i = tid; i < nvec; i += nt) {
        float4 v = row4[i];
        llrow[4 * i + 0] = v.x; llrow[4 * i + 1] = v.y;
        llrow[4 * i + 2] = v.z; llrow[4 * i + 3] = v.w;
      }
    } else {
      for (int i = tid; i < C; i += nt) llrow[i] = row[i];
    }
    __syncthreads();

    float nv[2];
    for (int u = 0; u < 2; ++u) {
      nv[u] = NEG_INF_F;
      int s = tid + u * nt;
      if (s < S) {
        float mm = NEG_INF_F, ss = 0.0f;
        int k = rs[u];
        const int e = re[u];
        for (; k + 3 < e; k += 4) {     // 4-wide: parallel loads, 5 exps / 4 arcs
          uint2 a0 = meta[k], a1 = meta[k + 1], a2 = meta[k + 2], a3 = meta[k + 3];
          float s0 = alpha[a0.x & 0xFFFFu] + __uint_as_float(a0.y) + llrow[a0.x >> 16];
          float s1 = alpha[a1.x & 0xFFFFu] + __uint_as_float(a1.y) + llrow[a1.x >> 16];
          float s2 = alpha[a2.x & 0xFFFFu] + __uint_as_float(a2.y) + llrow[a2.x >> 16];
          float s3 = alpha[a3.x & 0xFFFFu] + __uint_as_float(a3.y) + llrow[a3.x >> 16];
          float mc = fmaxf(fmaxf(s0, s1), fmaxf(s2, s3));
          float nm = fmaxf(mm, mc);
          ss = ss * __expf(mm - nm) +
               ((__expf(s0 - nm) + __expf(s1 - nm)) + (__expf(s2 - nm) + __expf(s3 - nm)));
          mm = nm;
        }
        for (; k < e; ++k) {
          uint2 a = meta[k];
          float sc = alpha[a.x & 0xFFFFu] + __uint_as_float(a.y) + llrow[a.x >> 16];
          float nm = fmaxf(mm, sc);
          ss = ss * __expf(mm - nm) + __expf(sc - nm);
          mm = nm;
        }
        nv[u] = (ss > 0.0f) ? (__logf(ss) + mm) : NEG_INF_F;
      }
    }
    __syncthreads();               // all reads of old alpha + llrow done
    for (int u = 0; u < 2; ++u) {
      int s = tid + u * nt;
      if (s < S) alpha[s] = nv[u];
    }
    __syncthreads();               // new alpha visible
  }

  // final logsumexp(alpha + final_logp)
  const int nwaves = nt >> 6;
  float lm = -3.0e38f;
  for (int s = tid; s < S; s += nt) lm = fmaxf(lm, alpha[s] + fin[s]);
  for (int off = 32; off; off >>= 1) lm = fmaxf(lm, __shfl_down(lm, off));
  if ((tid & 63) == 0) redbuf[tid >> 6] = lm;
  __syncthreads();
  if (tid < 64) {
    float v = (tid < nwaves) ? redbuf[tid] : -3.0e38f;
    for (int off = 32; off; off >>= 1) v = fmaxf(v, __shfl_down(v, off));
    if (tid == 0) redbuf[0] = v;
  }
  __syncthreads();
  const float M = redbuf[0];

  float ls = 0.0f;
  for (int s = tid; s < S; s += nt) ls += __expf(alpha[s] + fin[s] - M);
  for (int off = 32; off; off >>= 1) ls += __shfl_down(ls, off);
  __syncthreads();
  if ((tid & 63) == 0) redbuf[tid >> 6] = ls;
  __syncthreads();
  if (tid < 64) {
    float v = (tid < nwaves) ? redbuf[tid] : 0.0f;
    for (int off = 32; off; off >>= 1) v += __shfl_down(v, off);
    if (tid == 0) out_llh[(is_den ? 0 : B) + b] = __logf(v) + M;
  }
}

// ============================ fallback (atomic path, tiny ws) ============================

__device__ __forceinline__ unsigned enc_f(float x) {
  unsigned u = __float_as_uint(x);
  return u ^ (unsigned)(((int)u >> 31) | 0x80000000);
}
__device__ __forceinline__ float dec_f(unsigned e) {
  unsigned mask = ((int)e >= 0) ? 0xFFFFFFFFu : 0x80000000u;
  return __uint_as_float(e ^ mask);
}

__global__ __launch_bounds__(1024)
void fsa_forward_fallback(
    const float* __restrict__ ll, const int* __restrict__ seqlen,
    const int* __restrict__ den_src, const int* __restrict__ den_dst,
    const int* __restrict__ den_pdf, const float* __restrict__ den_w,
    int A_den, const float* __restrict__ den_init, const float* __restrict__ den_final, int S_den,
    const int* __restrict__ num_src, const int* __restrict__ num_dst,
    const int* __restrict__ num_pdf, const float* __restrict__ num_w,
    int A_num, const float* __restrict__ num_init, const float* __restrict__ num_final, int S_num,
    int T, int C, int B, float* __restrict__ out_llh)
{
  __shared__ float    alpha[MAX_S];
  __shared__ unsigned menc[MAX_S];
  __shared__ float    msafe[MAX_S];
  __shared__ float    ssum[MAX_S];
  __shared__ float    llrow[MAX_C];

  const int tid = threadIdx.x;
  const int nt  = blockDim.x;
  const bool is_den = ((int)blockIdx.x) < B;
  const int b = is_den ? (int)blockIdx.x : ((int)blockIdx.x - B);
  const int S = is_den ? S_den : S_num;
  const int A = is_den ? A_den : A_num;
  const float* init = is_den ? den_init  : num_init;
  const float* fin  = is_den ? den_final : num_final;
  const int*   asrc = is_den ? den_src  : (num_src + (size_t)b * A_num);
  const int*   adst = is_den ? den_dst  : (num_dst + (size_t)b * A_num);
  const int*   apdf = is_den ? den_pdf  : (num_pdf + (size_t)b * A_num);
  const float* aw   = is_den ? den_w    : (num_w   + (size_t)b * A_num);

  for (int s = tid; s < S; s += nt) { alpha[s] = init[s]; menc[s] = 0u; ssum[s] = 0.0f; }
  __syncthreads();

  const int L = seqlen[b];
  const float* llb = ll + ((size_t)b * T) * C;

  for (int t = 0; t < L; ++t) {
    const float* row = llb + (size_t)t * C;
    for (int i = tid; i < C; i += nt) llrow[i] = row[i];
    __syncthreads();
    for (int i = tid; i < A; i += nt) {
      float score = alpha[asrc[i]] + aw[i] + llrow[apdf[i]];
      atomicMax(&menc[adst[i]], enc_f(score));
    }
    __syncthreads();
    for (int s = tid; s < S; s += nt) {
      float m = dec_f(menc[s]);
      msafe[s] = (m > -5e29f) ? m : 0.0f;
    }
    __syncthreads();
    for (int i = tid; i < A; i += nt) {
      int d = adst[i];
      float score = alpha[asrc[i]] + aw[i] + llrow[apdf[i]];
      atomicAdd(&ssum[d], __expf(score - msafe[d]));
    }
    __syncthreads();
    for (int s = tid; s < S; s += nt) {
      float sum = ssum[s];
      alpha[s] = (sum > 0.0f) ? (__logf(sum) + msafe[s]) : NEG_INF_F;
      menc[s] = 0u; ssum[s] = 0.0f;
    }
    __syncthreads();
  }

  float lm = -3.0e38f;
  for (int s = tid; s < S; s += nt) lm = fmaxf(lm, alpha[s] + fin[s]);
  for (int off = 32; off; off >>= 1) lm = fmaxf(lm, __shfl_down(lm, off));
  const int nwaves = nt >> 6;
  if ((tid & 63) == 0) msafe[tid >> 6] = lm;
  __syncthreads();
  if (tid < 64) {
    float v = (tid < nwaves) ? msafe[tid] : -3.0e38f;
    for (int off = 32; off; off >>= 1) v = fmaxf(v, __shfl_down(v, off));
    if (tid == 0) msafe[MAX_S - 1] = v;
  }
  __syncthreads();
  const float M = msafe[MAX_S - 1];
  float ls = 0.0f;
  for (int s = tid; s < S; s += nt) ls += __expf(alpha[s] + fin[s] - M);
  for (int off = 32; off; off >>= 1) ls += __shfl_down(ls, off);
  if ((tid & 63) == 0) ssum[tid >> 6] = ls;
  __syncthreads();
  if (tid < 64) {
    float v = (tid < nwaves) ? ssum[tid] : 0.0f;
    for (int off = 32; off; off >>= 1) v += __shfl_down(v, off);
    if (tid == 0) out_llh[(is_den ? 0 : B) + b] = __logf(v) + M;
  }
}

// loss = sum_b (den_llh[b] - num_llh[b])
__global__ void final_loss_kernel(const float* __restrict__ llh, int B, float* __restrict__ out) {
  int lane = threadIdx.x;
  float v = (lane < B) ? (llh[lane] - llh[B + lane]) : 0.0f;
  for (int off = 32; off; off >>= 1) v += __shfl_down(v, off);
  if (lane == 0) out[0] = v;
}

extern "C" void kernel_launch(void* const* d_in, const int* in_sizes, int n_in,
                              void* d_out, int out_size, void* d_ws, size_t ws_size,
                              hipStream_t stream) {
  const float* ll        = (const float*)d_in[0];
  const int*   seqlen    = (const int*)  d_in[1];
  const int*   num_src   = (const int*)  d_in[2];
  const int*   num_dst   = (const int*)  d_in[3];
  const int*   num_pdf   = (const int*)  d_in[4];
  const float* num_w     = (const float*)d_in[5];
  const float* num_init  = (const float*)d_in[6];
  const float* num_final = (const float*)d_in[7];
  const int*   den_src   = (const int*)  d_in[8];
  const int*   den_dst   = (const int*)  d_in[9];
  const int*   den_pdf   = (const int*)  d_in[10];
  const float* den_w     = (const float*)d_in[11];
  const float* den_init  = (const float*)d_in[12];
  const float* den_final = (const float*)d_in[13];

  const int B     = in_sizes[1];
  const int A_num = in_sizes[2] / B;
  const int S_num = in_sizes[6];
  const int A_den = in_sizes[8];
  const int S_den = in_sizes[12];
  const int T     = 500;                       // problem spec
  const int C     = in_sizes[0] / (B * T);

  // workspace layout
  size_t off = 0;
  auto alloc = [&](size_t bytes, size_t align) -> size_t {
    off = (off + align - 1) / align * align;
    size_t r = off; off += bytes; return r;
  };
  size_t o_den_meta = alloc((size_t)A_den * 8, 8);
  size_t o_num_meta = alloc((size_t)B * A_num * 8, 8);
  size_t o_den_rp   = alloc((size_t)(S_den + 1) * 4, 4);
  size_t o_num_rp   = alloc((size_t)B * (S_num + 1) * 4, 4);
  size_t o_den_cnt  = alloc((size_t)S_den * 4, 4);
  size_t o_hist     = alloc((size_t)NCH * S_den * 4, 4);
  size_t o_num_cnt  = alloc((size_t)B * S_num * 4, 4);   // contiguous after hist -> one zero pass
  size_t o_llh      = alloc((size_t)2 * B * 4, 4);
  const bool use_csr = (off <= ws_size) && (S_den <= 2047) && (S_num <= 2047) && (C <= 65536);

  char* wsb = (char*)d_ws;
  float* llh = (float*)(wsb + (use_csr ? o_llh : 0));

  if (use_csr) {
    uint2* den_meta = (uint2*)(wsb + o_den_meta);
    uint2* num_meta = (uint2*)(wsb + o_num_meta);
    int*   den_rp   = (int*)(wsb + o_den_rp);
    int*   num_rp   = (int*)(wsb + o_num_rp);
    int*   den_cnt  = (int*)(wsb + o_den_cnt);
    int*   hist     = (int*)(wsb + o_hist);
    int*   num_cnt  = (int*)(wsb + o_num_cnt);

    const int chunk = (A_den + NCH - 1) / NCH;

    // zero hist + num_cnt in one pass (contiguous)
    int ztot = NCH * S_den + B * S_num;
    zero_kernel<<<(ztot + 255) / 256, 256, 0, stream>>>(hist, ztot);

    hist_chunk_kernel<<<NCH, 256, 0, stream>>>(den_dst, A_den, chunk, S_den, hist);
    hist_kernel<<<dim3((A_num + 255) / 256, B), 256, 0, stream>>>(num_dst, A_num, A_num, num_cnt, S_num);

    colsum_kernel<<<(S_den + 255) / 256, 256, 0, stream>>>(hist, NCH, S_den, den_cnt);
    scan_kernel<<<1, 1024, 0, stream>>>(den_cnt, den_rp, S_den);
    scan_kernel<<<B, 1024, 0, stream>>>(num_cnt, num_rp, S_num);

    off_kernel<<<(S_den + 255) / 256, 256, 0, stream>>>(hist, NCH, S_den, den_rp);
    fill_chunk_kernel<<<dim3((S_den + 255) / 256, NCH), 256, 0, stream>>>(
        den_src, den_dst, den_pdf, den_w, A_den, chunk, S_den, hist, den_meta);
    fill_kernel<<<dim3((S_num + 255) / 256, B), 256, 0, stream>>>(
        num_src, num_dst, num_pdf, num_w, A_num, A_num, num_rp, S_num, num_meta, A_num);

    fsa_forward_csr2<<<2 * B, 1024, 0, stream>>>(
        ll, seqlen, den_meta, den_rp, S_den, num_meta, num_rp, A_num, S_num,
        den_init, den_final, num_init, num_final, T, C, B, llh);
  } else {
    fsa_forward_fallback<<<2 * B, 1024, 0, stream>>>(
        ll, seqlen,
        den_src, den_dst, den_pdf, den_w, A_den, den_init, den_final, S_den,
        num_src, num_dst, num_pdf, num_w, A_num, num_init, num_final, S_num,
        T, C, B, llh);
  }

  final_loss_kernel<<<1, 64, 0, stream>>>(llh, B, (float*)d_out);
}

// Round 4
// 4359.849 us; speedup vs baseline: 9.2174x; 1.4478x over previous
//
#include <hip/hip_runtime.h>

#define NEG_INF_F (-1e30f)
#define MAX_S 2048
#define MAX_C 3008
#define NCH   128

// ============================ build helpers (deterministic) ============================

__global__ void zero_kernel(int* __restrict__ p, int n) {
  int i = blockIdx.x * blockDim.x + threadIdx.x;
  if (i < n) p[i] = 0;
}

// per-b histogram (numerator): grid (ceil(A/256), B)
__global__ void hist_kernel(const int* __restrict__ dst, int A, int A_stride,
                            int* __restrict__ cnt, int S) {
  int b = blockIdx.y;
  int i = blockIdx.x * blockDim.x + threadIdx.x;
  if (i < A) atomicAdd(&cnt[b * S + dst[(size_t)b * A_stride + i]], 1);
}

// chunked histogram (denominator): grid NCH blocks
__global__ void hist_chunk_kernel(const int* __restrict__ dst, int A, int chunk, int S,
                                  int* __restrict__ hist) {
  int c = blockIdx.x;
  int i1 = min(A, (c + 1) * chunk);
  for (int i = c * chunk + threadIdx.x; i < i1; i += blockDim.x)
    atomicAdd(&hist[c * S + dst[i]], 1);
}

__global__ void colsum_kernel(const int* __restrict__ hist, int nch, int S,
                              int* __restrict__ cnt) {
  int s = blockIdx.x * blockDim.x + threadIdx.x;
  if (s < S) {
    int t = 0;
    for (int c = 0; c < nch; ++c) t += hist[c * S + s];
    cnt[s] = t;
  }
}

// Stable in-degree rank (desc) -> slot permutation pairing heavy with light.
// perm[slot] = state occupying alpha slot; invperm[state] = slot.
__global__ __launch_bounds__(1024)
void rank_perm_kernel(const int* __restrict__ cnt, int S,
                      int* __restrict__ perm, int* __restrict__ invperm) {
  __shared__ int c[2048];
  __shared__ int R[2048];
  const int tid = threadIdx.x;
  for (int i = tid; i < 2048; i += 1024) c[i] = (i < S) ? cnt[i] : -1;
  __syncthreads();
  for (int u = 0; u < 2; ++u) {
    int s = tid + u * 1024;
    if (s < S) {
      int cs = c[s], r = 0;
      for (int j = 0; j < S; ++j) {
        int cj = c[j];
        r += (cj > cs) || (cj == cs && j < s);
      }
      R[r] = s;
    }
  }
  __syncthreads();
  for (int u = 0; u < 2; ++u) {
    int slot = tid + u * 1024;
    if (slot < S) {
      int state = (slot < 1024) ? R[slot] : R[S - 1 - (slot - 1024)];
      perm[slot] = state;
      invperm[state] = slot;
    }
  }
}

// padded per-slot counts over 2048 slots
__global__ void pc_kernel(const int* __restrict__ cnt, const int* __restrict__ perm,
                          int S, int* __restrict__ pc) {
  int slot = blockIdx.x * blockDim.x + threadIdx.x;
  if (slot < 2048) pc[slot] = (slot < S) ? ((cnt[perm[slot]] + 3) & ~3) : 0;
}

// numerator: padded counts
__global__ void padcnt_kernel(const int* __restrict__ cnt, int n, int* __restrict__ out) {
  int i = blockIdx.x * blockDim.x + threadIdx.x;
  if (i < n) out[i] = (cnt[i] + 3) & ~3;
}

// grid = nfsa blocks of 1024; counts over S entries (S <= 2048). Exclusive scan -> rp[S+1].
__global__ __launch_bounds__(1024) void scan_kernel(const int* __restrict__ cnt,
                                                    int* __restrict__ rp, int S) {
  __shared__ int buf[2][2048];
  const int tid = threadIdx.x;
  const int b = blockIdx.x;
  const int* c = cnt + (size_t)b * S;
  int* r = rp + (size_t)b * (S + 1);
  for (int u = 0; u < 2; ++u) {
    int i = tid + u * 1024;
    buf[0][i] = (i < S) ? c[i] : 0;
  }
  __syncthreads();
  int cur = 0;
  for (int off = 1; off < 2048; off <<= 1) {
    for (int u = 0; u < 2; ++u) {
      int i = tid + u * 1024;
      buf[cur ^ 1][i] = buf[cur][i] + ((i >= off) ? buf[cur][i - off] : 0);
    }
    __syncthreads();
    cur ^= 1;
  }
  for (int u = 0; u < 2; ++u) {
    int i = tid + u * 1024;
    if (i <= S) r[i] = (i == 0) ? 0 : buf[cur][i - 1];
  }
  if (tid == 0) r[S] = buf[cur][S - 1];
}

// hist[c][state] -> starting write offset for (chunk c, state), rows at rp[slot]
__global__ void off_perm_kernel(int* __restrict__ hist, int nch, int S,
                                const int* __restrict__ rp, const int* __restrict__ perm) {
  int slot = blockIdx.x * blockDim.x + threadIdx.x;
  if (slot < S) {
    int state = perm[slot];
    int run = rp[slot];
    for (int c = 0; c < nch; ++c) {
      int h = hist[c * S + state];
      hist[c * S + state] = run;
      run += h;
    }
  }
}

// fill pad arcs at row tails (den)
__global__ void pad_den_kernel(const int* __restrict__ rp, const int* __restrict__ cnt,
                               const int* __restrict__ perm, int S, uint2* __restrict__ meta) {
  int slot = blockIdx.x * blockDim.x + threadIdx.x;
  if (slot < S) {
    int p = rp[slot] + cnt[perm[slot]];
    int e = rp[slot + 1];
    uint2 pad = make_uint2(0u, __float_as_uint(NEG_INF_F));
    for (; p < e; ++p) meta[p] = pad;
  }
}

// grid (ceil(S/256), NCH): thread (state,c) scans chunk c in original order -> stable CSR.
// src rewritten to slot space via invperm.
__global__ void fill_chunk_kernel(const int* __restrict__ src, const int* __restrict__ dst,
                                  const int* __restrict__ pdf, const float* __restrict__ w,
                                  int A, int chunk, int S, int* __restrict__ hoff,
                                  const int* __restrict__ inv, uint2* __restrict__ meta) {
  int c = blockIdx.y;
  int s = blockIdx.x * blockDim.x + threadIdx.x;
  if (s >= S) return;
  int i1 = min(A, (c + 1) * chunk);
  int p = hoff[c * S + s];
  for (int i = c * chunk; i < i1; ++i) {
    if (dst[i] == s) {
      meta[p++] = make_uint2((unsigned)inv[src[i]] | ((unsigned)pdf[i] << 16),
                             __float_as_uint(w[i]));
    }
  }
}

// serial per-state fill + tail pad (numerator, tiny): grid (ceil(S/256), B)
__global__ void fill_kernel(const int* __restrict__ src, const int* __restrict__ dst,
                            const int* __restrict__ pdf, const float* __restrict__ w,
                            int A, int A_stride, const int* __restrict__ rp, int S,
                            uint2* __restrict__ meta, int meta_stride) {
  int b = blockIdx.y;
  int s = blockIdx.x * blockDim.x + threadIdx.x;
  if (s >= S) return;
  const int*   sb = src + (size_t)b * A_stride;
  const int*   db = dst + (size_t)b * A_stride;
  const int*   pb = pdf + (size_t)b * A_stride;
  const float* wb = w   + (size_t)b * A_stride;
  const int*   rpb = rp + (size_t)b * (S + 1);
  uint2* mb = meta + (size_t)b * meta_stride;
  int p = rpb[s];
  for (int i = 0; i < A; ++i) {
    if (db[i] == s) {
      mb[p++] = make_uint2((unsigned)sb[i] | ((unsigned)pb[i] << 16), __float_as_uint(wb[i]));
    }
  }
  uint2 pad = make_uint2(0u, __float_as_uint(NEG_INF_F));
  int e = rpb[s + 1];
  for (; p < e; ++p) mb[p] = pad;
}

// ============================ CSR forward v3 ============================
// One block per chain; rows padded to x4; uint4 meta; pipelined dual-acc LSE;
// double-buffered llrow with register prefetch; balanced slot permutation.
__global__ __launch_bounds__(1024)
void fsa_forward_csr3(const float* __restrict__ ll, const int* __restrict__ seqlen,
                      const uint2* __restrict__ den_meta, const int* __restrict__ den_rp,
                      const int* __restrict__ den_perm, int S_den,
                      const uint2* __restrict__ num_meta, const int* __restrict__ num_rp,
                      int num_stride, int S_num,
                      const float* __restrict__ den_init, const float* __restrict__ den_final,
                      const float* __restrict__ num_init, const float* __restrict__ num_final,
                      int T, int C, int B, float* __restrict__ out_llh)
{
  __shared__ float alpha[MAX_S];
  __shared__ float llrow[2 * MAX_C];
  __shared__ float redbuf[16];

  const int tid = threadIdx.x;
  const int nt  = blockDim.x;     // 1024
  const bool is_den = ((int)blockIdx.x) < B;
  const int b = is_den ? (int)blockIdx.x : ((int)blockIdx.x - B);
  const int S = is_den ? S_den : S_num;
  const float* init = is_den ? den_init  : num_init;
  const float* fin  = is_den ? den_final : num_final;
  const uint2* meta = is_den ? den_meta : (num_meta + (size_t)b * num_stride);
  const int*   rp   = is_den ? den_rp   : (num_rp   + (size_t)b * (S_num + 1));
  const int*   perm = is_den ? den_perm : nullptr;   // num: identity

  for (int s = tid; s < S; s += nt) alpha[s] = init[perm ? perm[s] : s];

  int rs[2] = {0, 0}, re[2] = {0, 0};
  for (int u = 0; u < 2; ++u) {
    int s = tid + u * nt;
    if (s < S) { rs[u] = rp[s]; re[u] = rp[s + 1]; }
  }

  const int L = seqlen[b];        // alpha frozen for t >= L -> stop there
  const float* llb = ll + ((size_t)b * T) * C;
  const int nvec = C >> 2;
  const bool v4 = ((C & 3) == 0) && ((((uintptr_t)llb) & 15) == 0);
  const bool pf = v4 && (C <= 4 * nt) && (C <= MAX_C);
  float* lbuf0 = llrow;
  float* lbuf1 = llrow + MAX_C;

  if (pf && L > 0) {
    const float4* r4 = (const float4*)llb;
    for (int i = tid; i < nvec; i += nt) ((float4*)lbuf0)[i] = r4[i];
  }
  __syncthreads();

  for (int t = 0; t < L; ++t) {
    float* lcur;
    if (pf) {
      lcur = (t & 1) ? lbuf1 : lbuf0;
    } else {
      lcur = lbuf0;
      const float* row = llb + (size_t)t * C;
      for (int i = tid; i < C; i += nt) lcur[i] = row[i];
      __syncthreads();
    }

    // prefetch next row into registers (hidden under the arc loop)
    float4 nx;
    const bool donx = pf && (t + 1 < L) && (tid < nvec);
    if (donx) nx = ((const float4*)(llb + (size_t)(t + 1) * C))[tid];

    float nv[2];
    for (int u = 0; u < 2; ++u) {
      nv[u] = NEG_INF_F;
      int s = tid + u * nt;
      if (s < S) {
        float mm0 = NEG_INF_F, ss0 = 0.0f, mm1 = NEG_INF_F, ss1 = 0.0f;
        const int k = rs[u];
        const int n4 = (re[u] - k) >> 2;          // rows padded to x4
        const uint4* p = (const uint4*)(meta + k); // 32B-aligned (k % 4 == 0)
        if (n4 > 0) {
          uint4 A = p[0], Bv = p[1];
          float t0 = alpha[A.x & 0xFFFFu] + __uint_as_float(A.y) + lcur[A.x >> 16];
          float t1 = alpha[A.z & 0xFFFFu] + __uint_as_float(A.w) + lcur[A.z >> 16];
          float t2 = alpha[Bv.x & 0xFFFFu] + __uint_as_float(Bv.y) + lcur[Bv.x >> 16];
          float t3 = alpha[Bv.z & 0xFFFFu] + __uint_as_float(Bv.w) + lcur[Bv.z >> 16];
          for (int c2 = 1; c2 < n4; ++c2) {
            uint4 A2 = p[2 * c2], B2 = p[2 * c2 + 1];
            float u0 = alpha[A2.x & 0xFFFFu] + __uint_as_float(A2.y) + lcur[A2.x >> 16];
            float u1 = alpha[A2.z & 0xFFFFu] + __uint_as_float(A2.w) + lcur[A2.z >> 16];
            float u2 = alpha[B2.x & 0xFFFFu] + __uint_as_float(B2.y) + lcur[B2.x >> 16];
            float u3 = alpha[B2.z & 0xFFFFu] + __uint_as_float(B2.w) + lcur[B2.z >> 16];
            float mc = fmaxf(fmaxf(t0, t1), fmaxf(t2, t3));
            if ((c2 & 1) != 0) {       // merge chunk c2-1 (even) into acc0
              float nm = fmaxf(mm0, mc);
              ss0 = ss0 * __expf(mm0 - nm) +
                    ((__expf(t0 - nm) + __expf(t1 - nm)) + (__expf(t2 - nm) + __expf(t3 - nm)));
              mm0 = nm;
            } else {                   // merge odd chunk into acc1
              float nm = fmaxf(mm1, mc);
              ss1 = ss1 * __expf(mm1 - nm) +
                    ((__expf(t0 - nm) + __expf(t1 - nm)) + (__expf(t2 - nm) + __expf(t3 - nm)));
              mm1 = nm;
            }
            t0 = u0; t1 = u1; t2 = u2; t3 = u3;
          }
          // merge last chunk (index n4-1)
          float mc = fmaxf(fmaxf(t0, t1), fmaxf(t2, t3));
          if ((n4 & 1) != 0) {         // last chunk even -> acc0
            float nm = fmaxf(mm0, mc);
            ss0 = ss0 * __expf(mm0 - nm) +
                  ((__expf(t0 - nm) + __expf(t1 - nm)) + (__expf(t2 - nm) + __expf(t3 - nm)));
            mm0 = nm;
          } else {
            float nm = fmaxf(mm1, mc);
            ss1 = ss1 * __expf(mm1 - nm) +
                  ((__expf(t0 - nm) + __expf(t1 - nm)) + (__expf(t2 - nm) + __expf(t3 - nm)));
            mm1 = nm;
          }
        }
        float nm = fmaxf(mm0, mm1);
        float ssc = ss0 * __expf(mm0 - nm) + ss1 * __expf(mm1 - nm);
        nv[u] = (ssc > 0.0f) ? (__logf(ssc) + nm) : NEG_INF_F;
      }
    }
    __syncthreads();               // all reads of old alpha + llrow done
    for (int u = 0; u < 2; ++u) {
      int s = tid + u * nt;
      if (s < S) alpha[s] = nv[u];
    }
    if (donx) {
      float* lnx = (t & 1) ? lbuf0 : lbuf1;
      ((float4*)lnx)[tid] = nx;
    }
    __syncthreads();               // new alpha + next row visible
  }

  // final logsumexp(alpha + final_logp)
  const int nwaves = nt >> 6;
  float lm = -3.0e38f;
  for (int s = tid; s < S; s += nt) lm = fmaxf(lm, alpha[s] + fin[perm ? perm[s] : s]);
  for (int off = 32; off; off >>= 1) lm = fmaxf(lm, __shfl_down(lm, off));
  if ((tid & 63) == 0) redbuf[tid >> 6] = lm;
  __syncthreads();
  if (tid < 64) {
    float v = (tid < nwaves) ? redbuf[tid] : -3.0e38f;
    for (int off = 32; off; off >>= 1) v = fmaxf(v, __shfl_down(v, off));
    if (tid == 0) redbuf[0] = v;
  }
  __syncthreads();
  const float M = redbuf[0];

  float ls = 0.0f;
  for (int s = tid; s < S; s += nt) ls += __expf(alpha[s] + fin[perm ? perm[s] : s] - M);
  for (int off = 32; off; off >>= 1) ls += __shfl_down(ls, off);
  __syncthreads();
  if ((tid & 63) == 0) redbuf[tid >> 6] = ls;
  __syncthreads();
  if (tid < 64) {
    float v = (tid < nwaves) ? redbuf[tid] : 0.0f;
    for (int off = 32; off; off >>= 1) v += __shfl_down(v, off);
    if (tid == 0) out_llh[(is_den ? 0 : B) + b] = __logf(v) + M;
  }
}

// ============================ fallback (atomic path, tiny ws) ============================

__device__ __forceinline__ unsigned enc_f(float x) {
  unsigned u = __float_as_uint(x);
  return u ^ (unsigned)(((int)u >> 31) | 0x80000000);
}
__device__ __forceinline__ float dec_f(unsigned e) {
  unsigned mask = ((int)e >= 0) ? 0xFFFFFFFFu : 0x80000000u;
  return __uint_as_float(e ^ mask);
}

__global__ __launch_bounds__(1024)
void fsa_forward_fallback(
    const float* __restrict__ ll, const int* __restrict__ seqlen,
    const int* __restrict__ den_src, const int* __restrict__ den_dst,
    const int* __restrict__ den_pdf, const float* __restrict__ den_w,
    int A_den, const float* __restrict__ den_init, const float* __restrict__ den_final, int S_den,
    const int* __restrict__ num_src, const int* __restrict__ num_dst,
    const int* __restrict__ num_pdf, const float* __restrict__ num_w,
    int A_num, const float* __restrict__ num_init, const float* __restrict__ num_final, int S_num,
    int T, int C, int B, float* __restrict__ out_llh)
{
  __shared__ float    alpha[MAX_S];
  __shared__ unsigned menc[MAX_S];
  __shared__ float    msafe[MAX_S];
  __shared__ float    ssum[MAX_S];
  __shared__ float    llrow[MAX_C];

  const int tid = threadIdx.x;
  const int nt  = blockDim.x;
  const bool is_den = ((int)blockIdx.x) < B;
  const int b = is_den ? (int)blockIdx.x : ((int)blockIdx.x - B);
  const int S = is_den ? S_den : S_num;
  const int A = is_den ? A_den : A_num;
  const float* init = is_den ? den_init  : num_init;
  const float* fin  = is_den ? den_final : num_final;
  const int*   asrc = is_den ? den_src  : (num_src + (size_t)b * A_num);
  const int*   adst = is_den ? den_dst  : (num_dst + (size_t)b * A_num);
  const int*   apdf = is_den ? den_pdf  : (num_pdf + (size_t)b * A_num);
  const float* aw   = is_den ? den_w    : (num_w   + (size_t)b * A_num);

  for (int s = tid; s < S; s += nt) { alpha[s] = init[s]; menc[s] = 0u; ssum[s] = 0.0f; }
  __syncthreads();

  const int L = seqlen[b];
  const float* llb = ll + ((size_t)b * T) * C;

  for (int t = 0; t < L; ++t) {
    const float* row = llb + (size_t)t * C;
    for (int i = tid; i < C; i += nt) llrow[i] = row[i];
    __syncthreads();
    for (int i = tid; i < A; i += nt) {
      float score = alpha[asrc[i]] + aw[i] + llrow[apdf[i]];
      atomicMax(&menc[adst[i]], enc_f(score));
    }
    __syncthreads();
    for (int s = tid; s < S; s += nt) {
      float m = dec_f(menc[s]);
      msafe[s] = (m > -5e29f) ? m : 0.0f;
    }
    __syncthreads();
    for (int i = tid; i < A; i += nt) {
      int d = adst[i];
      float score = alpha[asrc[i]] + aw[i] + llrow[apdf[i]];
      atomicAdd(&ssum[d], __expf(score - msafe[d]));
    }
    __syncthreads();
    for (int s = tid; s < S; s += nt) {
      float sum = ssum[s];
      alpha[s] = (sum > 0.0f) ? (__logf(sum) + msafe[s]) : NEG_INF_F;
      menc[s] = 0u; ssum[s] = 0.0f;
    }
    __syncthreads();
  }

  float lm = -3.0e38f;
  for (int s = tid; s < S; s += nt) lm = fmaxf(lm, alpha[s] + fin[s]);
  for (int off = 32; off; off >>= 1) lm = fmaxf(lm, __shfl_down(lm, off));
  const int nwaves = nt >> 6;
  if ((tid & 63) == 0) msafe[tid >> 6] = lm;
  __syncthreads();
  if (tid < 64) {
    float v = (tid < nwaves) ? msafe[tid] : -3.0e38f;
    for (int off = 32; off; off >>= 1) v = fmaxf(v, __shfl_down(v, off));
    if (tid == 0) msafe[MAX_S - 1] = v;
  }
  __syncthreads();
  const float M = msafe[MAX_S - 1];
  float ls = 0.0f;
  for (int s = tid; s < S; s += nt) ls += __expf(alpha[s] + fin[s] - M);
  for (int off = 32; off; off >>= 1) ls += __shfl_down(ls, off);
  if ((tid & 63) == 0) ssum[tid >> 6] = ls;
  __syncthreads();
  if (tid < 64) {
    float v = (tid < nwaves) ? ssum[tid] : 0.0f;
    for (int off = 32; off; off >>= 1) v += __shfl_down(v, off);
    if (tid == 0) out_llh[(is_den ? 0 : B) + b] = __logf(v) + M;
  }
}

// loss = sum_b (den_llh[b] - num_llh[b])
__global__ void final_loss_kernel(const float* __restrict__ llh, int B, float* __restrict__ out) {
  int lane = threadIdx.x;
  float v = (lane < B) ? (llh[lane] - llh[B + lane]) : 0.0f;
  for (int off = 32; off; off >>= 1) v += __shfl_down(v, off);
  if (lane == 0) out[0] = v;
}

extern "C" void kernel_launch(void* const* d_in, const int* in_sizes, int n_in,
                              void* d_out, int out_size, void* d_ws, size_t ws_size,
                              hipStream_t stream) {
  const float* ll        = (const float*)d_in[0];
  const int*   seqlen    = (const int*)  d_in[1];
  const int*   num_src   = (const int*)  d_in[2];
  const int*   num_dst   = (const int*)  d_in[3];
  const int*   num_pdf   = (const int*)  d_in[4];
  const float* num_w     = (const float*)d_in[5];
  const float* num_init  = (const float*)d_in[6];
  const float* num_final = (const float*)d_in[7];
  const int*   den_src   = (const int*)  d_in[8];
  const int*   den_dst   = (const int*)  d_in[9];
  const int*   den_pdf   = (const int*)  d_in[10];
  const float* den_w     = (const float*)d_in[11];
  const float* den_init  = (const float*)d_in[12];
  const float* den_final = (const float*)d_in[13];

  const int B     = in_sizes[1];
  const int A_num = in_sizes[2] / B;
  const int S_num = in_sizes[6];
  const int A_den = in_sizes[8];
  const int S_den = in_sizes[12];
  const int T     = 500;                       // problem spec
  const int C     = in_sizes[0] / (B * T);

  const int den_cap    = A_den + 3 * S_den + 64;     // padded capacity
  const int num_stride = A_num + 3 * S_num + 64;     // padded per-b capacity

  // workspace layout
  size_t off = 0;
  auto alloc = [&](size_t bytes, size_t align) -> size_t {
    off = (off + align - 1) / align * align;
    size_t r = off; off += bytes; return r;
  };
  size_t o_den_meta = alloc((size_t)den_cap * 8, 16);
  size_t o_num_meta = alloc((size_t)B * num_stride * 8, 16);
  size_t o_den_rp   = alloc((size_t)2049 * 4, 4);
  size_t o_num_rp   = alloc((size_t)B * (S_num + 1) * 4, 4);
  size_t o_den_cnt  = alloc((size_t)S_den * 4, 4);
  size_t o_perm     = alloc((size_t)2048 * 4, 4);
  size_t o_inv      = alloc((size_t)S_den * 4, 4);
  size_t o_pc       = alloc((size_t)2048 * 4, 4);
  size_t o_num_pc   = alloc((size_t)B * S_num * 4, 4);
  size_t o_hist     = alloc((size_t)NCH * S_den * 4, 4);   // zeroed region start
  size_t o_num_cnt  = alloc((size_t)B * S_num * 4, 4);     // contiguous with hist
  size_t o_llh      = alloc((size_t)2 * B * 4, 4);
  const bool use_csr = (off <= ws_size) && (S_den >= 1) && (S_den <= 2048) &&
                       (S_num >= 1) && (S_num <= 2048) && (C <= MAX_C);

  char* wsb = (char*)d_ws;
  float* llh = (float*)(wsb + (use_csr ? o_llh : 0));

  if (use_csr) {
    uint2* den_meta = (uint2*)(wsb + o_den_meta);
    uint2* num_meta = (uint2*)(wsb + o_num_meta);
    int*   den_rp   = (int*)(wsb + o_den_rp);
    int*   num_rp   = (int*)(wsb + o_num_rp);
    int*   den_cnt  = (int*)(wsb + o_den_cnt);
    int*   perm     = (int*)(wsb + o_perm);
    int*   inv      = (int*)(wsb + o_inv);
    int*   pc       = (int*)(wsb + o_pc);
    int*   num_pc   = (int*)(wsb + o_num_pc);
    int*   hist     = (int*)(wsb + o_hist);
    int*   num_cnt  = (int*)(wsb + o_num_cnt);

    const int chunk = (A_den + NCH - 1) / NCH;

    // zero hist + num_cnt (contiguous)
    int ztot = NCH * S_den + B * S_num;
    zero_kernel<<<(ztot + 255) / 256, 256, 0, stream>>>(hist, ztot);

    hist_chunk_kernel<<<NCH, 256, 0, stream>>>(den_dst, A_den, chunk, S_den, hist);
    hist_kernel<<<dim3((A_num + 255) / 256, B), 256, 0, stream>>>(num_dst, A_num, A_num,
                                                                  num_cnt, S_num);

    colsum_kernel<<<(S_den + 255) / 256, 256, 0, stream>>>(hist, NCH, S_den, den_cnt);
    rank_perm_kernel<<<1, 1024, 0, stream>>>(den_cnt, S_den, perm, inv);
    pc_kernel<<<8, 256, 0, stream>>>(den_cnt, perm, S_den, pc);
    scan_kernel<<<1, 1024, 0, stream>>>(pc, den_rp, 2048);

    padcnt_kernel<<<(B * S_num + 255) / 256, 256, 0, stream>>>(num_cnt, B * S_num, num_pc);
    scan_kernel<<<B, 1024, 0, stream>>>(num_pc, num_rp, S_num);

    off_perm_kernel<<<(S_den + 255) / 256, 256, 0, stream>>>(hist, NCH, S_den, den_rp, perm);
    pad_den_kernel<<<(S_den + 255) / 256, 256, 0, stream>>>(den_rp, den_cnt, perm, S_den, den_meta);
    fill_chunk_kernel<<<dim3((S_den + 255) / 256, NCH), 256, 0, stream>>>(
        den_src, den_dst, den_pdf, den_w, A_den, chunk, S_den, hist, inv, den_meta);
    fill_kernel<<<dim3((S_num + 255) / 256, B), 256, 0, stream>>>(
        num_src, num_dst, num_pdf, num_w, A_num, A_num, num_rp, S_num, num_meta, num_stride);

    fsa_forward_csr3<<<2 * B, 1024, 0, stream>>>(
        ll, seqlen, den_meta, den_rp, perm, S_den,
        num_meta, num_rp, num_stride, S_num,
        den_init, den_final, num_init, num_final, T, C, B, llh);
  } else {
    fsa_forward_fallback<<<2 * B, 1024, 0, stream>>>(
        ll, seqlen,
        den_src, den_dst, den_pdf, den_w, A_den, den_init, den_final, S_den,
        num_src, num_dst, num_pdf, num_w, A_num, num_init, num_final, S_num,
        T, C, B, llh);
  }

  final_loss_kernel<<<1, 64, 0, stream>>>(llh, B, (float*)d_out);
}